// Round 1
// baseline (136.864 us; speedup 1.0000x reference)
//
#include <hip/hip_runtime.h>
#include <math.h>

// Biquad highpass IIR over [B=128, C=2, T=65536] f32.
// Strategy: chunked-parallel IIR. Pole radius sqrt(a2)~0.8234 => zero-state
// warm-up of W=64 samples reduces chunk-boundary error to ~4e-5 (<< 1.06e-1
// threshold). Each thread owns one L=128-sample chunk; tiles of TS=32 samples
// are staged through LDS for coalesced global access (8 lanes = one 128B line).
// LDS row stride 33 floats => bank=(tid+t)%32, 2-way aliasing (free on CDNA4).

#define T_LEN   65536
#define L_CHUNK 128
#define W_WARM  64
#define TS      32
#define BLK     256
#define STRIDE  33           // LDS row stride (floats), +1 pad
#define CHUNK_SHIFT 9        // log2(T_LEN / L_CHUNK) = log2(512)

__global__ __launch_bounds__(BLK, 2)
void hp_biquad_kernel(const float* __restrict__ x, float* __restrict__ y,
                      float b0, float b1, float b2, float a1, float a2)
{
    __shared__ float lds[BLK * STRIDE];   // 33,792 B
    const int tid = threadIdx.x;
    const int blk = blockIdx.x;

    float x1 = 0.f, x2 = 0.f, y1 = 0.f, y2 = 0.f;

    const int NT = (W_WARM + L_CHUNK) / TS;   // 6 tiles: 2 warm-up, 4 stored
    for (int tile = 0; tile < NT; ++tile) {
        // ---- load phase: [BLK segs] x [TS floats], float4 granularity,
        // 8 consecutive lanes cover 128B contiguous => full line coalescing
        #pragma unroll
        for (int p = 0; p < (BLK * TS / 4) / BLK; ++p) {   // 8
            int q   = tid + p * BLK;
            int seg = q >> 3;               // TS/4 = 8 float4 per segment
            int off = (q & 7) << 2;         // float offset in tile
            int cg  = blk * BLK + seg;      // global chunk id
            int pos = cg * L_CHUNK - W_WARM + tile * TS + off;
            int cbase = (cg >> CHUNK_SHIFT) * T_LEN;  // channel base
            float4 v = make_float4(0.f, 0.f, 0.f, 0.f);
            if (pos >= cbase)               // zero-fill before channel start
                v = *(const float4*)(x + pos);
            int a = seg * STRIDE + off;
            lds[a] = v.x; lds[a + 1] = v.y; lds[a + 2] = v.z; lds[a + 3] = v.w;
        }
        __syncthreads();

        // ---- compute phase: serial biquad over my 32 samples, in-place
        {
            int base = tid * STRIDE;
            #pragma unroll
            for (int t = 0; t < TS; ++t) {
                float xv = lds[base + t];
                float yv = b0 * xv + b1 * x1 + b2 * x2 - a1 * y1 - a2 * y2;
                lds[base + t] = yv;
                x2 = x1; x1 = xv;
                y2 = y1; y1 = yv;
            }
        }
        __syncthreads();

        // ---- store phase (skip warm-up tiles), same coalesced mapping
        if (tile >= W_WARM / TS) {
            #pragma unroll
            for (int p = 0; p < (BLK * TS / 4) / BLK; ++p) {
                int q   = tid + p * BLK;
                int seg = q >> 3;
                int off = (q & 7) << 2;
                int cg  = blk * BLK + seg;
                int pos = cg * L_CHUNK - W_WARM + tile * TS + off;
                int a   = seg * STRIDE + off;
                float4 v = make_float4(lds[a], lds[a + 1], lds[a + 2], lds[a + 3]);
                *(float4*)(y + pos) = v;
            }
        }
        __syncthreads();
    }
}

extern "C" void kernel_launch(void* const* d_in, const int* in_sizes, int n_in,
                              void* d_out, int out_size, void* d_ws, size_t ws_size,
                              hipStream_t stream)
{
    const float* x = (const float*)d_in[0];
    float* y = (float*)d_out;

    // Coefficients: exact same double-precision formulas as the reference,
    // cast to f32 at the end (matches np.float32(b0/a0) etc.)
    const double SR = 16000.0, FLO = 200.0, FHI = 1200.0;
    const double freq   = 0.5 * (FLO + FHI);      // 700 Hz
    const double cutoff = freq / SR;
    const double q      = 0.70710678;
    const double w0 = 2.0 * M_PI * cutoff;
    const double cw = cos(w0), sw = sin(w0);
    const double alpha = sw / (2.0 * q);
    const double b0 = (1.0 + cw) / 2.0;
    const double b1 = -(1.0 + cw);
    const double b2 = (1.0 + cw) / 2.0;
    const double a0 = 1.0 + alpha;
    const double a1 = -2.0 * cw;
    const double a2 = 1.0 - alpha;
    const float fb0 = (float)(b0 / a0), fb1 = (float)(b1 / a0), fb2 = (float)(b2 / a0);
    const float fa1 = (float)(a1 / a0), fa2 = (float)(a2 / a0);

    const int total  = 128 * 2 * T_LEN;           // 16,777,216
    const int chunks = total / L_CHUNK;           // 131,072
    const int blocks = chunks / BLK;              // 512

    hp_biquad_kernel<<<blocks, BLK, 0, stream>>>(x, y, fb0, fb1, fb2, fa1, fa2);
    (void)in_sizes; (void)n_in; (void)out_size; (void)d_ws; (void)ws_size;
}

// Round 2
// 118.631 us; speedup vs baseline: 1.1537x; 1.1537x over previous
//
#include <hip/hip_runtime.h>
#include <math.h>

// Biquad highpass IIR over [B=128, C=2, T=65536] f32.
// R2: chunked-parallel IIR, wave-autonomous. Each WAVE owns 64 chunks of
// L=64 samples (+W=64 zero-state warm-up; pole radius 0.8234 => boundary
// error ~1e-4 << 0.106 threshold). No __syncthreads: cross-lane LDS
// visibility within one wave needs only lgkmcnt(0) (DS ops complete in
// order per wave), so prefetched global loads stay outstanding (no vmcnt
// drain). LDS layout: 32-float rows, float4 slot rotated by row
// (slot=(g+row)&7) => every access is aligned ds_*_b128 hitting all 32
// banks per 8-lane phase.

#define T_LEN   65536
#define L_CHUNK 64
#define W_WARM  64
#define TS      32
#define BLK     256                       // 4 independent waves / block
#define NT      ((W_WARM + L_CHUNK) / TS) // 4 tiles; tiles 2..3 stored
#define CHUNK_SHIFT 10                    // log2(T_LEN / L_CHUNK)
#define ROWS    64                        // chunks per wave
#define WLDS    (ROWS * TS)               // 2048 floats per wave

__device__ __forceinline__ void lds_fence() {
    // Waits all DS ops (in-order per wave => cross-lane visibility), does
    // NOT touch vmcnt, so prefetch loads remain in flight.
    asm volatile("s_waitcnt lgkmcnt(0)" ::: "memory");
}

__device__ __forceinline__ void load_tile(const float* __restrict__ x,
                                          int cg0, int tile, float4 pf[8],
                                          int lane)
{
    #pragma unroll
    for (int p = 0; p < 8; ++p) {
        int q   = lane + (p << 6);
        int seg = q >> 3;
        int g   = q & 7;
        int cg  = cg0 + seg;
        int pos = cg * L_CHUNK - W_WARM + tile * TS + (g << 2);
        int cbase = (cg >> CHUNK_SHIFT) * T_LEN;   // channel start
        float4 v = make_float4(0.f, 0.f, 0.f, 0.f);
        if (pos >= cbase)                           // zero state before channel
            v = *(const float4*)(x + pos);
        pf[p] = v;
    }
}

__global__ __launch_bounds__(BLK, 4)
void hp_biquad_kernel(const float* __restrict__ x, float* __restrict__ y,
                      float b0, float b1, float b2, float a1, float a2)
{
    __shared__ float lds[4 * WLDS];                 // 32 KiB / block
    const int tid  = threadIdx.x;
    const int lane = tid & 63;
    const int wv   = tid >> 6;
    float* wlds = lds + wv * WLDS;

    const int cg0 = (blockIdx.x * 4 + wv) * ROWS;   // first chunk of this wave

    float x1 = 0.f, x2 = 0.f, y1 = 0.f, y2 = 0.f;
    float4 pf[8];

    load_tile(x, cg0, 0, pf, lane);                 // prefetch tile 0

    for (int tile = 0; tile < NT; ++tile) {
        // ---- regs -> LDS (swizzled, b128) ----
        #pragma unroll
        for (int p = 0; p < 8; ++p) {
            int q    = lane + (p << 6);
            int seg  = q >> 3;
            int g    = q & 7;
            int slot = ((g + seg) & 7) << 2;
            *(float4*)&wlds[seg * TS + slot] = pf[p];
        }
        lds_fence();

        if (tile + 1 < NT)                          // prefetch next tile;
            load_tile(x, cg0, tile + 1, pf, lane);  // hidden under compute+store

        // ---- serial biquad over my row (32 samples), in place, b128 ----
        #pragma unroll
        for (int g = 0; g < 8; ++g) {
            int slot = ((g + lane) & 7) << 2;
            float4 v = *(float4*)&wlds[lane * TS + slot];
            float yv;
            yv = b0 * v.x + b1 * x1 + b2 * x2 - a1 * y1 - a2 * y2;
            x2 = x1; x1 = v.x; y2 = y1; y1 = yv; v.x = yv;
            yv = b0 * v.y + b1 * x1 + b2 * x2 - a1 * y1 - a2 * y2;
            x2 = x1; x1 = v.y; y2 = y1; y1 = yv; v.y = yv;
            yv = b0 * v.z + b1 * x1 + b2 * x2 - a1 * y1 - a2 * y2;
            x2 = x1; x1 = v.z; y2 = y1; y1 = yv; v.z = yv;
            yv = b0 * v.w + b1 * x1 + b2 * x2 - a1 * y1 - a2 * y2;
            x2 = x1; x1 = v.w; y2 = y1; y1 = yv; v.w = yv;
            *(float4*)&wlds[lane * TS + slot] = v;
        }
        lds_fence();

        // ---- coalesced store (skip warm-up tiles), b128 ----
        if (tile >= W_WARM / TS) {
            #pragma unroll
            for (int p = 0; p < 8; ++p) {
                int q    = lane + (p << 6);
                int seg  = q >> 3;
                int g    = q & 7;
                int slot = ((g + seg) & 7) << 2;
                float4 v = *(float4*)&wlds[seg * TS + slot];
                int cg   = cg0 + seg;
                int pos  = cg * L_CHUNK - W_WARM + tile * TS + (g << 2);
                *(float4*)(y + pos) = v;
            }
            lds_fence();   // reads done before next tile's LDS writes
        }
    }
}

extern "C" void kernel_launch(void* const* d_in, const int* in_sizes, int n_in,
                              void* d_out, int out_size, void* d_ws, size_t ws_size,
                              hipStream_t stream)
{
    const float* x = (const float*)d_in[0];
    float* y = (float*)d_out;

    // Same double-precision coefficient math as the reference, cast to f32.
    const double SR = 16000.0, FLO = 200.0, FHI = 1200.0;
    const double freq   = 0.5 * (FLO + FHI);      // 700 Hz
    const double cutoff = freq / SR;
    const double q      = 0.70710678;
    const double w0 = 2.0 * M_PI * cutoff;
    const double cw = cos(w0), sw = sin(w0);
    const double alpha = sw / (2.0 * q);
    const double b0 = (1.0 + cw) / 2.0;
    const double b1 = -(1.0 + cw);
    const double b2 = (1.0 + cw) / 2.0;
    const double a0 = 1.0 + alpha;
    const double a1 = -2.0 * cw;
    const double a2 = 1.0 - alpha;
    const float fb0 = (float)(b0 / a0), fb1 = (float)(b1 / a0), fb2 = (float)(b2 / a0);
    const float fa1 = (float)(a1 / a0), fa2 = (float)(a2 / a0);

    const int total  = 128 * 2 * T_LEN;            // 16,777,216 samples
    const int chunks = total / L_CHUNK;            // 262,144
    const int blocks = chunks / BLK;               // 1024 (256 chunks/block)

    hp_biquad_kernel<<<blocks, BLK, 0, stream>>>(x, y, fb0, fb1, fb2, fa1, fa2);
    (void)in_sizes; (void)n_in; (void)out_size; (void)d_ws; (void)ws_size;
}